// Round 10
// baseline (259.652 us; speedup 1.0000x reference)
//
#include <hip/hip_runtime.h>
#include <hip/hip_bf16.h>
#include <math.h>

typedef __attribute__((ext_vector_type(8))) short bf16x8;
typedef __attribute__((ext_vector_type(4))) float f32x4;

// Raw workgroup barrier WITHOUT the vmcnt(0) drain of __syncthreads().
__device__ __forceinline__ void wg_barrier() {
    asm volatile("s_waitcnt lgkmcnt(0)" ::: "memory");
    __builtin_amdgcn_s_barrier();
    asm volatile("" ::: "memory");
}

__device__ __forceinline__ bf16x8 pack_f32x8(float4 a, float4 b) {
    union { __hip_bfloat162 h2[4]; bf16x8 v; } u;
    u.h2[0] = __float22bfloat162_rn(make_float2(a.x, a.y));
    u.h2[1] = __float22bfloat162_rn(make_float2(a.z, a.w));
    u.h2[2] = __float22bfloat162_rn(make_float2(b.x, b.y));
    u.h2[3] = __float22bfloat162_rn(make_float2(b.z, b.w));
    return u.v;
}
__device__ __forceinline__ bf16x8 pack_f32p(const float* f) {
    union { __hip_bfloat162 h2[4]; bf16x8 v; } u;
    #pragma unroll
    for (int k = 0; k < 4; ++k)
        u.h2[k] = __float22bfloat162_rn(make_float2(f[2*k], f[2*k+1]));
    return u.v;
}

// ---------------- qkv projection ----------
__global__ void qkv_proj_kernel(const float* __restrict__ query,
                                const float* __restrict__ key,
                                const float* __restrict__ value,
                                const float* __restrict__ Wq, const float* __restrict__ bq,
                                const float* __restrict__ Wk, const float* __restrict__ bk,
                                const float* __restrict__ Wv, const float* __restrict__ bv,
                                float* __restrict__ qf, float* __restrict__ kf,
                                float* __restrict__ vf)
{
    const int mat = blockIdx.x >> 8;
    const int rb  = blockIdx.x & 255;
    const float* X; const float* W; const float* bias; float* dst;
    if (mat == 0)      { X = query; W = Wq; bias = bq; dst = qf; }
    else if (mat == 1) { X = key;   W = Wk; bias = bk; dst = kf; }
    else               { X = value; W = Wv; bias = bv; dst = vf; }

    __shared__ float sX[16][128];
    const int tid = threadIdx.x;
    const float* src = X + (size_t)rb * 16 * 128;
    #pragma unroll
    for (int i = 0; i < 8; ++i) {
        int idx = tid + i * 256;
        sX[idx >> 7][idx & 127] = src[idx];
    }
    __syncthreads();

    const int col = tid & 127;
    const int rg  = tid >> 7;
    float acc[8] = {0.f,0.f,0.f,0.f,0.f,0.f,0.f,0.f};
    #pragma unroll 8
    for (int e = 0; e < 128; ++e) {
        float w = W[e * 128 + col];
        #pragma unroll
        for (int r = 0; r < 8; ++r) acc[r] += sX[rg * 8 + r][e] * w;
    }
    float bb = bias[col];
    #pragma unroll
    for (int r = 0; r < 8; ++r)
        dst[(size_t)(rb * 16 + rg * 8 + r) * 128 + col] = acc[r] + bb;
}

// LDS layout (dynamic, 79008 B):
//   buf0:   [0,      32768)  f32 tile (64x128), src-swizzled
//   buf1:   [32768,  65536)  f32 tile            (prologue: sQK [256][9] f32)
//   sPfull: [65536,  73984)  bf16 [16][264]
//   sWt:    [73984,  78336)  bf16 [16][136]
//   sQs:    [78336,  78848)  f32 [128]
//   sLw:    [78848,  78976)  f32 [32]
//   sL:     [78976,  79008)  f32 [8]
// Swizzle: LDS 16B-unit (row, jj) holds global unit (row, jj ^ (row&7)).

#define STAGE(dstbuf, gbase)                                                      \
    {                                                                             \
        _Pragma("unroll")                                                         \
        for (int i_ = 0; i_ < 8; ++i_) {                                          \
            int row_ = (i_ * 4 + wv) * 2 + (lane >> 5);                           \
            int goff_ = row_ * 512 + (((lane & 31) ^ (row_ & 7)) << 4);           \
            __builtin_amdgcn_global_load_lds(                                     \
                (const __attribute__((address_space(1))) void*)((gbase) + goff_), \
                (__attribute__((address_space(3))) void*)((dstbuf) + (i_ * 4 + wv) * 1024), \
                16, 0, 0);                                                        \
        }                                                                         \
        __builtin_amdgcn_sched_barrier(0);                                        \
    }

#define TILE_STEP(T, CURB, NXTB, WAITSTR)                                         \
    {                                                                             \
        if ((T) < 3) STAGE(NXTB, relpe_b + ((T) + 1) * 32768)                     \
        asm volatile("s_waitcnt " WAITSTR ::: "memory");                          \
        __builtin_amdgcn_sched_barrier(0);                                        \
        wg_barrier();                                                             \
        const char* bA_ = (CURB);                                                 \
        /* GEMM1: s = qk + relpe @ Wtilde */                                      \
        f32x4 cs;                                                                 \
        cs[0] = qkr[(T)*4+0]; cs[1] = qkr[(T)*4+1];                               \
        cs[2] = qkr[(T)*4+2]; cs[3] = qkr[(T)*4+3];                               \
        _Pragma("unroll")                                                         \
        for (int kt = 0; kt < 4; ++kt) {                                          \
            int u0 = kt * 8 + koff * 2;                                           \
            float4 fa0 = *(const float4*)(bA_ + rowa_b + ((u0 ^ xr) << 4));       \
            float4 fa1 = *(const float4*)(bA_ + rowa_b + (((u0 + 1) ^ xr) << 4)); \
            bf16x8 af = pack_f32x8(fa0, fa1);                                     \
            bf16x8 bw = *(const bf16x8*)&sWt[arow][kt * 32 + koff * 8];           \
            cs = __builtin_amdgcn_mfma_f32_16x16x32_bf16(af, bw, cs, 0, 0, 0);    \
        }                                                                         \
        if (arow < 8) {                                                           \
            float p0 = __expf(cs[0]), p1 = __expf(cs[1]);                         \
            float p2 = __expf(cs[2]), p3 = __expf(cs[3]);                         \
            l_acc += (p0 + p1) + (p2 + p3);                                       \
            union { __hip_bfloat162 h2[2]; uint2 u; } pk;                         \
            pk.h2[0] = __float22bfloat162_rn(make_float2(p0, p1));                \
            pk.h2[1] = __float22bfloat162_rn(make_float2(p2, p3));                \
            *(uint2*)&sPfull[arow][(T) * 64 + wv * 16 + koff * 4] = pk.u;         \
        }                                                                         \
        wg_barrier();                                                             \
        /* GEMM2: pr += P^T @ relpe_tile */                                       \
        _Pragma("unroll")                                                         \
        for (int kt = 0; kt < 2; ++kt) {                                          \
            bf16x8 ap = *(const bf16x8*)&sPfull[arow][(T) * 64 + kt * 32 + koff * 8]; \
            float f0[8], f1[8];                                                   \
            _Pragma("unroll")                                                     \
            for (int j = 0; j < 8; ++j) {                                         \
                int rb_ = kt * 16384 + koff * 4096 + j * 512;                     \
                f0[j] = *(const float*)(bA_ + rb_ + ((colu0 ^ j) << 4) + colw0);  \
                f1[j] = *(const float*)(bA_ + rb_ + ((colu1 ^ j) << 4) + colw0);  \
            }                                                                     \
            bf16x8 b0 = pack_f32p(f0), b1 = pack_f32p(f1);                        \
            pr0 = __builtin_amdgcn_mfma_f32_16x16x32_bf16(ap, b0, pr0, 0, 0, 0);  \
            pr1 = __builtin_amdgcn_mfma_f32_16x16x32_bf16(ap, b1, pr1, 0, 0, 0);  \
        }                                                                         \
        wg_barrier();                                                             \
    }

__global__ __launch_bounds__(256) void mha_main_kernel(
    const float* __restrict__ relpe,
    const float* __restrict__ mask,
    const float* __restrict__ qf,
    const float* __restrict__ kf,
    const float* __restrict__ vf,
    const float* __restrict__ Wpe, const float* __restrict__ bpe,
    const float* __restrict__ Wo,  const float* __restrict__ bo,
    float* __restrict__ out)
{
    extern __shared__ char smem[];
    char* buf0 = smem;
    char* buf1 = smem + 32768;
    __hip_bfloat16 (*sPfull)[264] = (__hip_bfloat16(*)[264])(smem + 65536);
    __hip_bfloat16 (*sWt)[136]    = (__hip_bfloat16(*)[136])(smem + 73984);
    float* sQs = (float*)(smem + 78336);
    float* sLw = (float*)(smem + 78848);
    float* sL  = (float*)(smem + 78976);

    const int tid  = threadIdx.x;
    const int lane = tid & 63;
    const int wv   = tid >> 6;
    const int bid  = ((blockIdx.x & 7) << 9) | (blockIdx.x >> 3);  // XCD swizzle
    const int b    = bid >> 8;
    const int n    = bid & 255;
    const size_t bn = (size_t)(b * 256 + n);
    const int arow = lane & 15;
    const int koff = lane >> 4;

    const char* relpe_b = (const char*)relpe + bn * 131072;  // 256*128*4

    // ---- start tile-0 DMA immediately
    STAGE(buf0, relpe_b)

    if (tid < 128) sQs[tid] = qf[bn * 128 + tid] * 0.25f;
    wg_barrier();

    // ---- Wtilde[e][h] (stored transposed, bf16)
    #pragma unroll
    for (int o = tid; o < 1024; o += 256) {
        int h = o >> 7, e = o & 127;
        const float4* wr = (const float4*)(Wpe + (size_t)e * 128 + h * 16);
        float4 w0 = wr[0], w1 = wr[1], w2 = wr[2], w3 = wr[3];
        const float* qh = &sQs[h * 16];
        float acc = w0.x*qh[0]+w0.y*qh[1]+w0.z*qh[2]+w0.w*qh[3]
                  + w1.x*qh[4]+w1.y*qh[5]+w1.z*qh[6]+w1.w*qh[7]
                  + w2.x*qh[8]+w2.y*qh[9]+w2.z*qh[10]+w2.w*qh[11]
                  + w3.x*qh[12]+w3.y*qh[13]+w3.z*qh[14]+w3.w*qh[15];
        sWt[h][e] = __float2bfloat16(acc);
    }

    // ---- qk + cb + mask into sQK (aliased in buf1), then into registers
    float (*sQK)[9] = (float(*)[9])buf1;
    {
        const int hsc = tid >> 5, ml = tid & 31;
        float cb = 0.f;
        #pragma unroll
        for (int d = 0; d < 16; ++d) cb += bpe[hsc * 16 + d] * sQs[hsc * 16 + d];
        #pragma unroll
        for (int i = 0; i < 8; ++i) {
            int m = i * 32 + ml;
            const float4* k4 = (const float4*)(kf + ((size_t)(b * 256) + m) * 128 + hsc * 16);
            float4 ka = k4[0], kb = k4[1], kc = k4[2], kd = k4[3];
            const float* qh = &sQs[hsc * 16];
            float s = ka.x*qh[0]+ka.y*qh[1]+ka.z*qh[2]+ka.w*qh[3]
                    + kb.x*qh[4]+kb.y*qh[5]+kb.z*qh[6]+kb.w*qh[7]
                    + kc.x*qh[8]+kc.y*qh[9]+kc.z*qh[10]+kc.w*qh[11]
                    + kd.x*qh[12]+kd.y*qh[13]+kd.z*qh[14]+kd.w*qh[15];
            sQK[m][hsc] = s + cb + mask[bn * 256 + m];
        }
    }
    wg_barrier();

    float qkr[16];
    #pragma unroll
    for (int t2 = 0; t2 < 4; ++t2)
        #pragma unroll
        for (int r = 0; r < 4; ++r)
            qkr[t2 * 4 + r] = (arow < 8)
                ? sQK[t2 * 64 + wv * 16 + koff * 4 + r][arow] : 0.f;
    wg_barrier();   // buf1 free for tile-1 DMA

    float l_acc = 0.f;
    f32x4 pr0 = {}, pr1 = {};
    const int rowa_b = (wv * 16 + arow) * 512;
    const int xr     = (wv * 16 + arow) & 7;
    const int colu0  = (wv * 32 + arow) >> 2;
    const int colw0  = ((wv * 32 + arow) & 3) * 4;
    const int colu1  = colu0 + 4;

    TILE_STEP(0, buf0, buf1, "vmcnt(8)")
    TILE_STEP(1, buf1, buf0, "vmcnt(8)")
    TILE_STEP(2, buf0, buf1, "vmcnt(8)")
    TILE_STEP(3, buf1, buf0, "vmcnt(0)")

    // ================= epilogue (buf0 reused) =================
    {
        float lw = l_acc;
        lw += __shfl_xor(lw, 16);
        lw += __shfl_xor(lw, 32);
        if (koff == 0 && arow < 8) sLw[wv * 8 + arow] = lw;
    }
    float* sPrE = (float*)buf0;             // [8][132]
    float* sRed = (float*)(buf0 + 4352);    // [128]
    float* sOutF= (float*)(buf0 + 4864);    // [128]
    #pragma unroll
    for (int r = 0; r < 4; ++r) {
        int hh = koff * 4 + r;
        if (hh < 8) {
            sPrE[hh * 132 + wv * 32 + arow]      = pr0[r];
            sPrE[hh * 132 + wv * 32 + 16 + arow] = pr1[r];
        }
    }
    __syncthreads();
    if (tid < 8) sL[tid] = sLw[tid] + sLw[8 + tid] + sLw[16 + tid] + sLw[24 + tid];
    __syncthreads();

    const int e = tid & 127, half = tid >> 7, hh2 = e >> 4;

    float oa = 0.f;
    {
        const float* vp = vf + ((size_t)(b * 256) + half * 128) * 128 + e;
        const __hip_bfloat16* pp = &sPfull[hh2][half * 128];
        #pragma unroll 8
        for (int mm = 0; mm < 128; ++mm)
            oa += __bfloat162float(pp[mm]) * vp[(size_t)mm * 128];
    }
    float ype = 0.f;
    {
        const float* wp  = Wpe + (size_t)(half * 64) * 128 + e;
        const float* prh = &sPrE[hh2 * 132 + half * 64];
        #pragma unroll 8
        for (int ee = 0; ee < 64; ++ee) ype += prh[ee] * wp[(size_t)ee * 128];
    }
    if (half) sRed[e] = oa + ype;
    __syncthreads();
    if (!half) sOutF[e] = (oa + ype + sRed[e]) / sL[hh2] + bpe[e];
    __syncthreads();

    float y = 0.f;
    {
        const float* wo = Wo + (size_t)(half * 64) * 128 + e;
        #pragma unroll 8
        for (int ee = 0; ee < 64; ++ee) y += sOutF[half * 64 + ee] * wo[(size_t)ee * 128];
    }
    if (half) sRed[e] = y;
    __syncthreads();
    if (!half) out[bn * 128 + e] = y + sRed[e] + bo[e];
}

extern "C" void kernel_launch(void* const* d_in, const int* in_sizes, int n_in,
                              void* d_out, int out_size, void* d_ws, size_t ws_size,
                              hipStream_t stream)
{
    const float* query = (const float*)d_in[0];
    const float* key   = (const float*)d_in[1];
    const float* value = (const float*)d_in[2];
    const float* relpe = (const float*)d_in[3];
    const float* mask  = (const float*)d_in[4];
    const float* Wq  = (const float*)d_in[5];
    const float* bq  = (const float*)d_in[6];
    const float* Wk  = (const float*)d_in[7];
    const float* bk  = (const float*)d_in[8];
    const float* Wv  = (const float*)d_in[9];
    const float* bv  = (const float*)d_in[10];
    const float* Wpe = (const float*)d_in[11];
    const float* bpe = (const float*)d_in[12];
    const float* Wo  = (const float*)d_in[13];
    const float* bo  = (const float*)d_in[14];
    float* out = (float*)d_out;

    float* qf = (float*)d_ws;
    float* kf = qf + 16 * 256 * 128;
    float* vf = kf + 16 * 256 * 128;

    // Raise dynamic-LDS cap (host attribute set; graph-capture-safe, idempotent)
    static bool attr_done = false;
    (void)hipFuncSetAttribute((const void*)mha_main_kernel,
                              hipFuncAttributeMaxDynamicSharedMemorySize, 79008);

    qkv_proj_kernel<<<dim3(768), dim3(256), 0, stream>>>(
        query, key, value, Wq, bq, Wk, bk, Wv, bv, qf, kf, vf);
    mha_main_kernel<<<dim3(4096), dim3(256), 79008, stream>>>(
        relpe, mask, qf, kf, vf, Wpe, bpe, Wo, bo, out);
}